// Round 1
// baseline (533.722 us; speedup 1.0000x reference)
//
#include <hip/hip_runtime.h>
#include <hip/hip_bf16.h>
#include <math.h>

typedef __attribute__((ext_vector_type(8))) short short8;
typedef __attribute__((ext_vector_type(4))) float f32x4;
typedef __attribute__((ext_vector_type(4))) unsigned short us4;

#define KDIM 150528
#define NT_TILES 10
#define KCHUNKS 24
#define STEPS 98
#define HDIM 1280
#define MDIM 256

__device__ __forceinline__ unsigned short f2bf(float f) {
  unsigned int u = __float_as_uint(f);
  u += 0x7fffu + ((u >> 16) & 1u);  // RNE
  return (unsigned short)(u >> 16);
}

// ---------------------------------------------------------------------------
// K1: split-K GEMM  P[kc][m][n] = sum_{k in chunk kc} X[m,k] * W[n,k]
// X = xf (256 x 150528), W = Wb (1280 x 150528), both K-contiguous (NT gemm).
// Tile: 256x128, BK=64, 8 waves (4m x 2n), each wave 64x64 -> acc 4x4 frags.
// fp32 -> bf16 conversion in-register during staging; XOR-swizzled LDS.
// ---------------------------------------------------------------------------
__global__ __launch_bounds__(512, 2) void k_gemm(
    const float* __restrict__ X, const float* __restrict__ W,
    float* __restrict__ P) {
  extern __shared__ char smem[];
  const int tid = threadIdx.x;
  const int bid = blockIdx.x;
  const int nt = bid % NT_TILES;   // same-kc blocks adjacent -> concurrent x reads
  const int kc = bid / NT_TILES;
  const long k0 = (long)kc * (64 * STEPS);

  // staging: thread -> (row = tid>>4 [+32*i], 4 consecutive k at (tid&15)*4)
  const int srow = tid >> 4;
  const float* xA = X + (long)srow * KDIM + k0 + ((tid & 15) << 2);
  const float* wB = W + (long)(nt * 128 + srow) * KDIM + k0 + ((tid & 15) << 2);
  const int sbyte = (tid & 15) << 3;  // byte col in LDS row (bf16)

  const int lane = tid & 63;
  const int wv = tid >> 6;
  const int wm = wv >> 1, wn = wv & 1;
  const int frow = lane & 15;
  const int fkb = (lane >> 4) << 4;  // k-group byte offset

  f32x4 acc[4][4];
#pragma unroll
  for (int i = 0; i < 4; ++i)
#pragma unroll
    for (int j = 0; j < 4; ++j) acc[i][j] = (f32x4){0.f, 0.f, 0.f, 0.f};

  f32x4 av[8], bv[4];
  // prologue: stage step 0 into buf 0
#pragma unroll
  for (int i = 0; i < 8; ++i) av[i] = *(const f32x4*)(xA + (long)(i * 32) * KDIM);
#pragma unroll
  for (int i = 0; i < 4; ++i) bv[i] = *(const f32x4*)(wB + (long)(i * 32) * KDIM);
  {
    char* A = smem;
    char* B = smem + 32768;
#pragma unroll
    for (int i = 0; i < 8; ++i) {
      const int row = srow + i * 32;
      const int addr = row * 128 + (sbyte ^ ((row & 7) << 4));
      us4 p = {f2bf(av[i].x), f2bf(av[i].y), f2bf(av[i].z), f2bf(av[i].w)};
      *(us4*)(A + addr) = p;
    }
#pragma unroll
    for (int i = 0; i < 4; ++i) {
      const int row = srow + i * 32;
      const int addr = row * 128 + (sbyte ^ ((row & 7) << 4));
      us4 p = {f2bf(bv[i].x), f2bf(bv[i].y), f2bf(bv[i].z), f2bf(bv[i].w)};
      *(us4*)(B + addr) = p;
    }
  }
  __syncthreads();

  for (int t = 0; t < STEPS; ++t) {
    const int cur = t & 1;
    const bool has = (t + 1 < STEPS);
    if (has) {  // issue next-step global loads early (hide under MFMA)
      const long off = (long)(t + 1) * 64;
#pragma unroll
      for (int i = 0; i < 8; ++i)
        av[i] = *(const f32x4*)(xA + (long)(i * 32) * KDIM + off);
#pragma unroll
      for (int i = 0; i < 4; ++i)
        bv[i] = *(const f32x4*)(wB + (long)(i * 32) * KDIM + off);
    }
    const char* A = smem + cur * 49152;
    const char* B = A + 32768;
#pragma unroll
    for (int ks = 0; ks < 2; ++ks) {
      short8 fa[4], fb[4];
#pragma unroll
      for (int i = 0; i < 4; ++i) {
        const int row = wm * 64 + i * 16 + frow;
        const int addr = row * 128 + (((ks << 6) + fkb) ^ ((row & 7) << 4));
        fa[i] = *(const short8*)(A + addr);
      }
#pragma unroll
      for (int j = 0; j < 4; ++j) {
        const int row = wn * 64 + j * 16 + frow;
        const int addr = row * 128 + (((ks << 6) + fkb) ^ ((row & 7) << 4));
        fb[j] = *(const short8*)(B + addr);
      }
#pragma unroll
      for (int i = 0; i < 4; ++i)
#pragma unroll
        for (int j = 0; j < 4; ++j)
          acc[i][j] = __builtin_amdgcn_mfma_f32_16x16x32_bf16(fa[i], fb[j],
                                                              acc[i][j], 0, 0, 0);
    }
    if (has) {  // cvt + write next buffer (write-late)
      char* An = smem + (cur ^ 1) * 49152;
      char* Bn = An + 32768;
#pragma unroll
      for (int i = 0; i < 8; ++i) {
        const int row = srow + i * 32;
        const int addr = row * 128 + (sbyte ^ ((row & 7) << 4));
        us4 p = {f2bf(av[i].x), f2bf(av[i].y), f2bf(av[i].z), f2bf(av[i].w)};
        *(us4*)(An + addr) = p;
      }
#pragma unroll
      for (int i = 0; i < 4; ++i) {
        const int row = srow + i * 32;
        const int addr = row * 128 + (sbyte ^ ((row & 7) << 4));
        us4 p = {f2bf(bv[i].x), f2bf(bv[i].y), f2bf(bv[i].z), f2bf(bv[i].w)};
        *(us4*)(Bn + addr) = p;
      }
    }
    __syncthreads();
  }

  // epilogue: C/D frag layout col=lane&15, row=(lane>>4)*4+r  [m89]
  float* Pc = P + (long)kc * (MDIM * HDIM) + nt * 128;
  const int rb = wm * 64 + ((lane >> 4) << 2);
  const int cb = wn * 64 + frow;
#pragma unroll
  for (int i = 0; i < 4; ++i)
#pragma unroll
    for (int j = 0; j < 4; ++j) {
      const int col = cb + j * 16;
#pragma unroll
      for (int r = 0; r < 4; ++r)
        Pc[(long)(rb + i * 16 + r) * HDIM + col] = acc[i][j][r];
    }
}

// ---------------------------------------------------------------------------
// K2: S4D kernel table  ktab[h][l] = 2 * sum_n C*(exp(dtA)-1)/A * exp(dtA*l)
// ---------------------------------------------------------------------------
__global__ __launch_bounds__(256) void k_s4d(
    const float* __restrict__ log_dt, const float* __restrict__ lar,
    const float* __restrict__ C, float* __restrict__ ktab) {
  const int h = blockIdx.x * 256 + threadIdx.x;
  if (h >= HDIM) return;
  const float dt = expf(log_dt[h]);
  float acc[64];
#pragma unroll
  for (int l = 0; l < 64; ++l) acc[l] = 0.f;
  for (int n = 0; n < 32; ++n) {
    const float A = -expf(lar[h * 32 + n]);
    const float dtA = A * dt;
    const float Cb = C[h * 32 + n] * expm1f(dtA) / A;
    const float e = expf(dtA);
    float p = 1.f;
#pragma unroll
    for (int l = 0; l < 64; ++l) { acc[l] += Cb * p; p *= e; }
  }
#pragma unroll
  for (int l = 0; l < 64; ++l) ktab[h * 64 + l] = 2.f * acc[l];
}

// ---------------------------------------------------------------------------
// K3: reduce split-K partials + causal conv at l=63 + D skip + exact GELU
// y63[b][h] = gelu( sum_m u[b,m,h]*k[h,63-m] + D[h]*u[b,63,h] ), u = sum_kc P + bb
// ---------------------------------------------------------------------------
__global__ __launch_bounds__(256) void k_conv(
    const float* __restrict__ P, const float* __restrict__ ktab,
    const float* __restrict__ bb, const float* __restrict__ Dv,
    float* __restrict__ y63) {
  __shared__ float kt[64 * 65];  // +1 pad: stride-65 kills bank conflicts
  const int t = threadIdx.x;
  const int hw = blockIdx.x * 64;
  for (int i = t; i < 4096; i += 256)
    kt[(i >> 6) * 65 + (i & 63)] = ktab[(hw + (i >> 6)) * 64 + (i & 63)];
  __syncthreads();
  const int hl = t & 63, b = t >> 6;
  const int h = hw + hl;
  const float bbv = bb[h];
  float y = 0.f, u63 = 0.f;
  for (int m = 0; m < 64; ++m) {
    float u = bbv;
    const float* p = P + (long)(b * 64 + m) * HDIM + h;
#pragma unroll
    for (int c = 0; c < KCHUNKS; ++c) u += p[(long)c * (MDIM * HDIM)];
    if (m == 63) u63 = u;
    y += u * kt[hl * 65 + (63 - m)];
  }
  y += Dv[h] * u63;
  y63[b * HDIM + h] = 0.5f * y * (1.f + erff(y * 0.70710678118654752f));
}

// ---------------------------------------------------------------------------
// K4: z = Wc @ y63 + bc (only l=63 column), gate: last = a * sigmoid(g)
// ---------------------------------------------------------------------------
__global__ __launch_bounds__(256) void k_gate(
    const float* __restrict__ y63, const float* __restrict__ Wc,
    const float* __restrict__ bc, float* __restrict__ lastv) {
  __shared__ float ys[4 * HDIM];
  const int t = threadIdx.x;
  for (int i = t; i < 4 * HDIM; i += 256) ys[i] = y63[i];
  __syncthreads();
  const int hl = t & 63, b = t >> 6;
  const int h = blockIdx.x * 64 + hl;
  const float* wa = Wc + (long)h * HDIM;
  const float* wg = Wc + (long)(HDIM + h) * HDIM;
  const float* yb = ys + b * HDIM;
  float za = bc[h], zg = bc[HDIM + h];
  for (int j = 0; j < HDIM; j += 4) {
    f32x4 a4 = *(const f32x4*)(wa + j);
    f32x4 g4 = *(const f32x4*)(wg + j);
    const float y0 = yb[j], y1 = yb[j + 1], y2 = yb[j + 2], y3 = yb[j + 3];
    za += a4.x * y0 + a4.y * y1 + a4.z * y2 + a4.w * y3;
    zg += g4.x * y0 + g4.y * y1 + g4.z * y2 + g4.w * y3;
  }
  lastv[b * HDIM + h] = za / (1.f + expf(-zg));
}

// ---------------------------------------------------------------------------
// K5: head  h1 = relu(last @ W1^T + b1); out = h1 @ W2^T + b2  (one block per b)
// ---------------------------------------------------------------------------
__global__ __launch_bounds__(64) void k_head(
    const float* __restrict__ lastv, const float* __restrict__ W1,
    const float* __restrict__ b1, const float* __restrict__ W2,
    const float* __restrict__ b2, float* __restrict__ out) {
  __shared__ float ll[HDIM];
  __shared__ float h1[64];
  const int b = blockIdx.x, t = threadIdx.x;
  for (int i = t; i < HDIM; i += 64) ll[i] = lastv[b * HDIM + i];
  __syncthreads();
  {
    const float* w = W1 + t * HDIM;
    float s = b1[t];
    for (int j = 0; j < HDIM; j += 4) {
      f32x4 wvv = *(const f32x4*)(w + j);
      s += wvv.x * ll[j] + wvv.y * ll[j + 1] + wvv.z * ll[j + 2] + wvv.w * ll[j + 3];
    }
    h1[t] = fmaxf(s, 0.f);
  }
  __syncthreads();
  if (t < 60) {
    const float* w = W2 + t * 64;
    float o = b2[t];
#pragma unroll
    for (int r = 0; r < 64; ++r) o += w[r] * h1[r];
    out[b * 60 + t] = o;
  }
}

extern "C" void kernel_launch(void* const* d_in, const int* in_sizes, int n_in,
                              void* d_out, int out_size, void* d_ws, size_t ws_size,
                              hipStream_t stream) {
  const float* x   = (const float*)d_in[0];
  const float* Wb  = (const float*)d_in[1];
  const float* bb  = (const float*)d_in[2];
  const float* ldt = (const float*)d_in[3];
  const float* C   = (const float*)d_in[4];
  const float* lar = (const float*)d_in[5];
  const float* Dv  = (const float*)d_in[6];
  const float* Wc  = (const float*)d_in[7];
  const float* bc  = (const float*)d_in[8];
  const float* W1  = (const float*)d_in[9];
  const float* b1  = (const float*)d_in[10];
  const float* W2  = (const float*)d_in[11];
  const float* b2  = (const float*)d_in[12];
  float* out = (float*)d_out;

  float* P     = (float*)d_ws;                        // 24*256*1280 f32 = 31.5 MB
  float* ktab  = P + (long)KCHUNKS * MDIM * HDIM;     // 1280*64
  float* y63   = ktab + HDIM * 64;                    // 4*1280
  float* lastv = y63 + 4 * HDIM;                      // 4*1280

  (void)hipFuncSetAttribute(reinterpret_cast<const void*>(k_gemm),
                            hipFuncAttributeMaxDynamicSharedMemorySize, 98304);

  k_s4d<<<5, 256, 0, stream>>>(ldt, lar, C, ktab);
  k_gemm<<<NT_TILES * KCHUNKS, 512, 98304, stream>>>(x, Wb, P);
  k_conv<<<20, 256, 0, stream>>>(P, ktab, bb, Dv, y63);
  k_gate<<<20, 256, 0, stream>>>(y63, Wc, bc, lastv);
  k_head<<<4, 64, 0, stream>>>(lastv, W1, b1, W2, b2, out);
}

// Round 2
// 413.091 us; speedup vs baseline: 1.2920x; 1.2920x over previous
//
#include <hip/hip_runtime.h>
#include <hip/hip_bf16.h>
#include <math.h>

typedef __attribute__((ext_vector_type(8))) short short8;
typedef __attribute__((ext_vector_type(4))) float f32x4;

#define KDIM 150528
#define NT_TILES 10
#define MT_TILES 2
#define KCHUNKS 24
#define STEPS 98          // 6272 / 64
#define HDIM 1280
#define MDIM 256
#define PSTRIDE (MDIM * HDIM)

// packed fp32x2 -> bf16x2 RNE, single HW instruction (no builtin on gfx950)
__device__ __forceinline__ uint2 pk4(f32x4 v) {
  uint2 r;
  asm("v_cvt_pk_bf16_f32 %0, %2, %3\n\t"
      "v_cvt_pk_bf16_f32 %1, %4, %5"
      : "=&v"(r.x), "=&v"(r.y)
      : "v"(v.x), "v"(v.y), "v"(v.z), "v"(v.w));
  return r;
}

// ---------------------------------------------------------------------------
// K1: split-K GEMM  P[kc][m][n] += X[m,k]*W[n,k] over k-chunk kc.
// 128x128 tile, BK=64, 256 thr (4 waves 2m x 2n), dbuf LDS 64KB -> 2 blk/CU.
// fp32->bf16 via v_cvt_pk_bf16_f32 during staging; XOR-swizzled LDS rows.
// ---------------------------------------------------------------------------
__global__ __launch_bounds__(256, 2) void k_gemm(
    const float* __restrict__ X, const float* __restrict__ W,
    float* __restrict__ P) {
  extern __shared__ char smem[];
  // XCD-chunked bijective swizzle (480 % 8 == 0): kc-major within an XCD chunk
  const int swz = (blockIdx.x & 7) * 60 + (blockIdx.x >> 3);
  const int kc = swz / 20;
  const int rem = swz % 20;
  const int mt = rem / 10;
  const int nt = rem % 10;
  const long k0 = (long)kc * (64 * STEPS);

  const int tid = threadIdx.x;
  const int srow = tid >> 4;                 // 0..15
  const int scol = (tid & 15) << 2;          // 0..60 floats
  const float* xA = X + (long)(mt * 128 + srow) * KDIM + k0 + scol;
  const float* wB = W + (long)(nt * 128 + srow) * KDIM + k0 + scol;
  const int sbyte = (tid & 15) << 3;         // byte col in bf16 LDS row

  const int lane = tid & 63;
  const int wv = tid >> 6;
  const int wm = wv >> 1, wn = wv & 1;
  const int frow = lane & 15;
  const int fkb = (lane >> 4) << 4;

  f32x4 acc[4][4];
#pragma unroll
  for (int i = 0; i < 4; ++i)
#pragma unroll
    for (int j = 0; j < 4; ++j) acc[i][j] = (f32x4){0.f, 0.f, 0.f, 0.f};

  f32x4 av[8], bv[8];
#pragma unroll
  for (int i = 0; i < 8; ++i) {
    av[i] = *(const f32x4*)(xA + (long)(i * 16) * KDIM);
    bv[i] = *(const f32x4*)(wB + (long)(i * 16) * KDIM);
  }
  {
    char* A = smem;
    char* B = smem + 16384;
#pragma unroll
    for (int i = 0; i < 8; ++i) {
      const int row = srow + i * 16;
      const int addr = row * 128 + (sbyte ^ ((row & 7) << 4));
      *(uint2*)(A + addr) = pk4(av[i]);
      *(uint2*)(B + addr) = pk4(bv[i]);
    }
  }
  __syncthreads();

  for (int t = 0; t < STEPS; ++t) {
    const int cur = t & 1;
    const bool has = (t + 1 < STEPS);
    if (has) {  // issue next step's loads early (hide under MFMA)
      const long off = (long)(t + 1) * 64;
#pragma unroll
      for (int i = 0; i < 8; ++i) {
        av[i] = *(const f32x4*)(xA + (long)(i * 16) * KDIM + off);
        bv[i] = *(const f32x4*)(wB + (long)(i * 16) * KDIM + off);
      }
    }
    const char* A = smem + cur * 32768;
    const char* B = A + 16384;
#pragma unroll
    for (int ks = 0; ks < 2; ++ks) {
      short8 fa[4], fb[4];
#pragma unroll
      for (int i = 0; i < 4; ++i) {
        const int ra = wm * 64 + i * 16 + frow;
        fa[i] = *(const short8*)(A + ra * 128 +
                                 (((ks << 6) + fkb) ^ ((ra & 7) << 4)));
        const int rb2 = wn * 64 + i * 16 + frow;
        fb[i] = *(const short8*)(B + rb2 * 128 +
                                 (((ks << 6) + fkb) ^ ((rb2 & 7) << 4)));
      }
#pragma unroll
      for (int i = 0; i < 4; ++i)
#pragma unroll
        for (int j = 0; j < 4; ++j)
          acc[i][j] = __builtin_amdgcn_mfma_f32_16x16x32_bf16(fa[i], fb[j],
                                                              acc[i][j], 0, 0, 0);
    }
    if (has) {  // convert + write next buffer (write-late)
      char* An = smem + (cur ^ 1) * 32768;
      char* Bn = An + 16384;
#pragma unroll
      for (int i = 0; i < 8; ++i) {
        const int row = srow + i * 16;
        const int addr = row * 128 + (sbyte ^ ((row & 7) << 4));
        *(uint2*)(An + addr) = pk4(av[i]);
        *(uint2*)(Bn + addr) = pk4(bv[i]);
      }
    }
    __syncthreads();
  }

  // C/D layout: col=lane&15, row=(lane>>4)*4+r  [m89]
  float* Pc = P + (long)kc * PSTRIDE + (long)mt * 128 * HDIM + nt * 128;
  const int rb = wm * 64 + ((lane >> 4) << 2);
  const int cb = wn * 64 + frow;
#pragma unroll
  for (int i = 0; i < 4; ++i)
#pragma unroll
    for (int j = 0; j < 4; ++j) {
      const int col = cb + j * 16;
#pragma unroll
      for (int r = 0; r < 4; ++r)
        Pc[(long)(rb + i * 16 + r) * HDIM + col] = acc[i][j][r];
    }
}

// ---------------------------------------------------------------------------
// K2: S4D kernel table, one thread per (h,l) — no serial chains.
// ---------------------------------------------------------------------------
__global__ __launch_bounds__(256) void k_s4d(
    const float* __restrict__ log_dt, const float* __restrict__ lar,
    const float* __restrict__ C, float* __restrict__ ktab) {
  const int idx = blockIdx.x * 256 + threadIdx.x;  // 1280*64
  const int h = idx >> 6, l = idx & 63;
  const float dt = expf(log_dt[h]);
  const float fl = (float)l;
  float acc = 0.f;
#pragma unroll 4
  for (int n = 0; n < 32; ++n) {
    const float A = -expf(lar[h * 32 + n]);
    const float dtA = A * dt;
    const float Cb = C[h * 32 + n] * expm1f(dtA) / A;
    acc += Cb * expf(dtA * fl);
  }
  ktab[idx] = 2.f * acc;
}

// ---------------------------------------------------------------------------
// K3: split-K reduce  U[m][h] = bb[h] + sum_kc P  (full-chip parallel)
// ---------------------------------------------------------------------------
__global__ __launch_bounds__(256) void k_red(
    const float* __restrict__ P, const float* __restrict__ bb,
    float* __restrict__ U) {
  const int idx = blockIdx.x * 256 + threadIdx.x;  // 256*1280
  float s = bb[idx % HDIM];
#pragma unroll
  for (int c = 0; c < KCHUNKS; ++c) s += P[(long)c * PSTRIDE + idx];
  U[idx] = s;
}

// ---------------------------------------------------------------------------
// K4: causal conv at l=63 + D skip + exact GELU (reads tiny U)
// ---------------------------------------------------------------------------
__global__ __launch_bounds__(256) void k_conv(
    const float* __restrict__ U, const float* __restrict__ ktab,
    const float* __restrict__ Dv, float* __restrict__ y63) {
  __shared__ float kt[64 * 65];
  const int t = threadIdx.x;
  const int hw = blockIdx.x * 64;
  for (int i = t; i < 4096; i += 256)
    kt[(i >> 6) * 65 + (i & 63)] = ktab[(hw + (i >> 6)) * 64 + (i & 63)];
  __syncthreads();
  const int hl = t & 63, b = t >> 6;
  const int h = hw + hl;
  float y = 0.f;
  for (int m = 0; m < 64; ++m)
    y += U[(long)(b * 64 + m) * HDIM + h] * kt[hl * 65 + (63 - m)];
  y += Dv[h] * U[(long)(b * 64 + 63) * HDIM + h];
  y63[b * HDIM + h] = 0.5f * y * (1.f + erff(y * 0.70710678118654752f));
}

// ---------------------------------------------------------------------------
// K5: gating z=Wc@y63+bc, last = a*sigmoid(g). One wave per h-row, both
// halves (a at row r, g at row r+H) in the same block.
// ---------------------------------------------------------------------------
__global__ __launch_bounds__(64) void k_gate(
    const float* __restrict__ y63, const float* __restrict__ Wc,
    const float* __restrict__ bc, float* __restrict__ lastv) {
  const int r = blockIdx.x;       // 0..1279
  const int l = threadIdx.x;      // 0..63
  const float* wa = Wc + (long)r * HDIM;
  const float* wg = Wc + (long)(HDIM + r) * HDIM;
  float sa[4] = {0.f, 0.f, 0.f, 0.f}, sg[4] = {0.f, 0.f, 0.f, 0.f};
#pragma unroll
  for (int seg = 0; seg < 5; ++seg) {
    const int j = seg * 256 + l * 4;
    const f32x4 a4 = *(const f32x4*)(wa + j);
    const f32x4 g4 = *(const f32x4*)(wg + j);
#pragma unroll
    for (int b = 0; b < 4; ++b) {
      const f32x4 yv = *(const f32x4*)(y63 + b * HDIM + j);
      sa[b] += a4.x * yv.x + a4.y * yv.y + a4.z * yv.z + a4.w * yv.w;
      sg[b] += g4.x * yv.x + g4.y * yv.y + g4.z * yv.z + g4.w * yv.w;
    }
  }
#pragma unroll
  for (int off = 32; off; off >>= 1)
#pragma unroll
    for (int b = 0; b < 4; ++b) {
      sa[b] += __shfl_down(sa[b], off);
      sg[b] += __shfl_down(sg[b], off);
    }
  if (l == 0) {
    const float ba = bc[r], bg = bc[HDIM + r];
#pragma unroll
    for (int b = 0; b < 4; ++b) {
      const float za = ba + sa[b], zg = bg + sg[b];
      lastv[b * HDIM + r] = za / (1.f + expf(-zg));
    }
  }
}

// ---------------------------------------------------------------------------
// K6: head  h1 = relu(last @ W1^T + b1); out = h1 @ W2^T + b2
// ---------------------------------------------------------------------------
__global__ __launch_bounds__(64) void k_head(
    const float* __restrict__ lastv, const float* __restrict__ W1,
    const float* __restrict__ b1, const float* __restrict__ W2,
    const float* __restrict__ b2, float* __restrict__ out) {
  __shared__ float ll[HDIM];
  __shared__ float h1[64];
  const int b = blockIdx.x, t = threadIdx.x;
  for (int i = t; i < HDIM; i += 64) ll[i] = lastv[b * HDIM + i];
  __syncthreads();
  {
    const float* w = W1 + t * HDIM;
    float s = b1[t];
    for (int j = 0; j < HDIM; j += 4) {
      const f32x4 wv = *(const f32x4*)(w + j);
      s += wv.x * ll[j] + wv.y * ll[j + 1] + wv.z * ll[j + 2] + wv.w * ll[j + 3];
    }
    h1[t] = fmaxf(s, 0.f);
  }
  __syncthreads();
  if (t < 60) {
    const float* w = W2 + t * 64;
    float o = b2[t];
#pragma unroll
    for (int r = 0; r < 64; ++r) o += w[r] * h1[r];
    out[b * 60 + t] = o;
  }
}

extern "C" void kernel_launch(void* const* d_in, const int* in_sizes, int n_in,
                              void* d_out, int out_size, void* d_ws, size_t ws_size,
                              hipStream_t stream) {
  const float* x   = (const float*)d_in[0];
  const float* Wb  = (const float*)d_in[1];
  const float* bb  = (const float*)d_in[2];
  const float* ldt = (const float*)d_in[3];
  const float* C   = (const float*)d_in[4];
  const float* lar = (const float*)d_in[5];
  const float* Dv  = (const float*)d_in[6];
  const float* Wc  = (const float*)d_in[7];
  const float* bc  = (const float*)d_in[8];
  const float* W1  = (const float*)d_in[9];
  const float* b1  = (const float*)d_in[10];
  const float* W2  = (const float*)d_in[11];
  const float* b2  = (const float*)d_in[12];
  float* out = (float*)d_out;

  float* P     = (float*)d_ws;                     // 24*256*1280 f32 = 31.5 MB
  float* ktab  = P + (long)KCHUNKS * PSTRIDE;      // 1280*64
  float* U     = ktab + HDIM * 64;                 // 256*1280
  float* y63   = U + PSTRIDE;                      // 4*1280
  float* lastv = y63 + 4 * HDIM;                   // 4*1280

  (void)hipFuncSetAttribute(reinterpret_cast<const void*>(k_gemm),
                            hipFuncAttributeMaxDynamicSharedMemorySize, 65536);

  k_s4d<<<320, 256, 0, stream>>>(ldt, lar, C, ktab);
  k_gemm<<<NT_TILES * MT_TILES * KCHUNKS, 256, 65536, stream>>>(x, Wb, P);
  k_red<<<PSTRIDE / 256, 256, 0, stream>>>(P, bb, U);
  k_conv<<<20, 256, 0, stream>>>(U, ktab, Dv, y63);
  k_gate<<<HDIM, 64, 0, stream>>>(y63, Wc, bc, lastv);
  k_head<<<4, 64, 0, stream>>>(lastv, W1, b1, W2, b2, out);
}

// Round 3
// 356.837 us; speedup vs baseline: 1.4957x; 1.1576x over previous
//
#include <hip/hip_runtime.h>
#include <hip/hip_bf16.h>
#include <math.h>

typedef __attribute__((ext_vector_type(8))) short short8;
typedef __attribute__((ext_vector_type(4))) float f32x4;

#define KDIM 150528
#define NT_TILES 10
#define MT_TILES 2
#define KCHUNKS 24
#define STEPS 98          // 6272 / 64
#define HDIM 1280
#define MDIM 256
#define PSTRIDE (MDIM * HDIM)

// packed fp32x2 -> bf16x2 RNE, single HW instruction (no builtin on gfx950)
__device__ __forceinline__ uint2 pk4(f32x4 v) {
  uint2 r;
  asm("v_cvt_pk_bf16_f32 %0, %2, %3\n\t"
      "v_cvt_pk_bf16_f32 %1, %4, %5"
      : "=&v"(r.x), "=&v"(r.y)
      : "v"(v.x), "v"(v.y), "v"(v.z), "v"(v.w));
  return r;
}

// ---------------------------------------------------------------------------
// K1: split-K GEMM  P[kc][m][n] += X[m,k]*W[n,k] over k-chunk kc.
// 128x128 tile, BK=64, 512 thr (8 waves, wave tile 32x64), dbuf LDS 64KB.
// ~110 VGPR -> 4 waves/SIMD, 2 blocks/CU: TLP covers the vmcnt stalls.
// fp32->bf16 via v_cvt_pk_bf16_f32 during staging; XOR-swizzled LDS rows.
// ---------------------------------------------------------------------------
__global__ __launch_bounds__(512, 4) void k_gemm(
    const float* __restrict__ X, const float* __restrict__ W,
    float* __restrict__ P) {
  extern __shared__ char smem[];
  // XCD-chunked bijective swizzle (480 % 8 == 0): kc-major within an XCD chunk
  const int swz = (blockIdx.x & 7) * 60 + (blockIdx.x >> 3);
  const int kc = swz / 20;
  const int rem = swz % 20;
  const int mt = rem / 10;
  const int nt = rem % 10;
  const long k0 = (long)kc * (64 * STEPS);

  const int tid = threadIdx.x;
  const int srow = tid >> 4;                 // 0..31
  const int scol = (tid & 15) << 2;          // float col 0..60
  const float* xA = X + (long)(mt * 128 + srow) * KDIM + k0 + scol;
  const float* wB = W + (long)(nt * 128 + srow) * KDIM + k0 + scol;
  const int sbyte = (tid & 15) << 3;         // byte col in bf16 LDS row

  const int lane = tid & 63;
  const int wv = tid >> 6;                   // 0..7
  const int wm = wv >> 1, wn = wv & 1;       // 4 x 2 wave grid, tile 32m x 64n
  const int frow = lane & 15;
  const int fkb = (lane >> 4) << 4;

  f32x4 acc[2][4];
#pragma unroll
  for (int i = 0; i < 2; ++i)
#pragma unroll
    for (int j = 0; j < 4; ++j) acc[i][j] = (f32x4){0.f, 0.f, 0.f, 0.f};

  f32x4 av[4], bv[4];
#pragma unroll
  for (int i = 0; i < 4; ++i) {
    av[i] = *(const f32x4*)(xA + (long)(i * 32) * KDIM);
    bv[i] = *(const f32x4*)(wB + (long)(i * 32) * KDIM);
  }
  {
    char* A = smem;
    char* B = smem + 16384;
#pragma unroll
    for (int i = 0; i < 4; ++i) {
      const int row = srow + i * 32;
      const int addr = row * 128 + (sbyte ^ ((row & 7) << 4));
      *(uint2*)(A + addr) = pk4(av[i]);
      *(uint2*)(B + addr) = pk4(bv[i]);
    }
  }
  __syncthreads();

  for (int t = 0; t < STEPS; ++t) {
    const int cur = t & 1;
    const bool has = (t + 1 < STEPS);
    if (has) {  // issue next step's loads early (hide under MFMA + sibling waves)
      const long off = (long)(t + 1) * 64;
#pragma unroll
      for (int i = 0; i < 4; ++i) {
        av[i] = *(const f32x4*)(xA + (long)(i * 32) * KDIM + off);
        bv[i] = *(const f32x4*)(wB + (long)(i * 32) * KDIM + off);
      }
    }
    const char* A = smem + cur * 32768;
    const char* B = A + 16384;
#pragma unroll
    for (int ks = 0; ks < 2; ++ks) {
      short8 fa[2], fb[4];
#pragma unroll
      for (int i = 0; i < 2; ++i) {
        const int ra = wm * 32 + i * 16 + frow;
        fa[i] = *(const short8*)(A + ra * 128 +
                                 (((ks << 6) + fkb) ^ ((ra & 7) << 4)));
      }
#pragma unroll
      for (int j = 0; j < 4; ++j) {
        const int rb2 = wn * 64 + j * 16 + frow;
        fb[j] = *(const short8*)(B + rb2 * 128 +
                                 (((ks << 6) + fkb) ^ ((rb2 & 7) << 4)));
      }
#pragma unroll
      for (int i = 0; i < 2; ++i)
#pragma unroll
        for (int j = 0; j < 4; ++j)
          acc[i][j] = __builtin_amdgcn_mfma_f32_16x16x32_bf16(fa[i], fb[j],
                                                              acc[i][j], 0, 0, 0);
    }
    if (has) {  // convert + write next buffer (write-late)
      char* An = smem + (cur ^ 1) * 32768;
      char* Bn = An + 16384;
#pragma unroll
      for (int i = 0; i < 4; ++i) {
        const int row = srow + i * 32;
        const int addr = row * 128 + (sbyte ^ ((row & 7) << 4));
        *(uint2*)(An + addr) = pk4(av[i]);
        *(uint2*)(Bn + addr) = pk4(bv[i]);
      }
    }
    __syncthreads();
  }

  // C/D layout: col=lane&15, row=(lane>>4)*4+r  [m89]
  float* Pc = P + (long)kc * PSTRIDE + (long)mt * 128 * HDIM + nt * 128;
  const int rb = wm * 32 + ((lane >> 4) << 2);
  const int cb = wn * 64 + frow;
#pragma unroll
  for (int i = 0; i < 2; ++i)
#pragma unroll
    for (int j = 0; j < 4; ++j) {
      const int col = cb + j * 16;
#pragma unroll
      for (int r = 0; r < 4; ++r)
        Pc[(long)(rb + i * 16 + r) * HDIM + col] = acc[i][j][r];
    }
}

// ---------------------------------------------------------------------------
// K2: S4D kernel table, one thread per (h,l) — no serial chains.
// ---------------------------------------------------------------------------
__global__ __launch_bounds__(256) void k_s4d(
    const float* __restrict__ log_dt, const float* __restrict__ lar,
    const float* __restrict__ C, float* __restrict__ ktab) {
  const int idx = blockIdx.x * 256 + threadIdx.x;  // 1280*64
  const int h = idx >> 6, l = idx & 63;
  const float dt = expf(log_dt[h]);
  const float fl = (float)l;
  float acc = 0.f;
#pragma unroll 4
  for (int n = 0; n < 32; ++n) {
    const float A = -expf(lar[h * 32 + n]);
    const float dtA = A * dt;
    const float Cb = C[h * 32 + n] * expm1f(dtA) / A;
    acc += Cb * expf(dtA * fl);
  }
  ktab[idx] = 2.f * acc;
}

// ---------------------------------------------------------------------------
// K3: split-K reduce  U[m][h] = bb[h] + sum_kc P  (full-chip parallel)
// ---------------------------------------------------------------------------
__global__ __launch_bounds__(256) void k_red(
    const float* __restrict__ P, const float* __restrict__ bb,
    float* __restrict__ U) {
  const int idx = blockIdx.x * 256 + threadIdx.x;  // 256*1280
  float s = bb[idx % HDIM];
#pragma unroll
  for (int c = 0; c < KCHUNKS; ++c) s += P[(long)c * PSTRIDE + idx];
  U[idx] = s;
}

// ---------------------------------------------------------------------------
// K4: causal conv at l=63 + D skip + exact GELU (reads tiny U)
// ---------------------------------------------------------------------------
__global__ __launch_bounds__(256) void k_conv(
    const float* __restrict__ U, const float* __restrict__ ktab,
    const float* __restrict__ Dv, float* __restrict__ y63) {
  __shared__ float kt[64 * 65];
  const int t = threadIdx.x;
  const int hw = blockIdx.x * 64;
  for (int i = t; i < 4096; i += 256)
    kt[(i >> 6) * 65 + (i & 63)] = ktab[(hw + (i >> 6)) * 64 + (i & 63)];
  __syncthreads();
  const int hl = t & 63, b = t >> 6;
  const int h = hw + hl;
  float y = 0.f;
  for (int m = 0; m < 64; ++m)
    y += U[(long)(b * 64 + m) * HDIM + h] * kt[hl * 65 + (63 - m)];
  y += Dv[h] * U[(long)(b * 64 + 63) * HDIM + h];
  y63[b * HDIM + h] = 0.5f * y * (1.f + erff(y * 0.70710678118654752f));
}

// ---------------------------------------------------------------------------
// K5: gating z=Wc@y63+bc, last = a*sigmoid(g). One wave per h-row.
// ---------------------------------------------------------------------------
__global__ __launch_bounds__(64) void k_gate(
    const float* __restrict__ y63, const float* __restrict__ Wc,
    const float* __restrict__ bc, float* __restrict__ lastv) {
  const int r = blockIdx.x;       // 0..1279
  const int l = threadIdx.x;      // 0..63
  const float* wa = Wc + (long)r * HDIM;
  const float* wg = Wc + (long)(HDIM + r) * HDIM;
  float sa[4] = {0.f, 0.f, 0.f, 0.f}, sg[4] = {0.f, 0.f, 0.f, 0.f};
#pragma unroll
  for (int seg = 0; seg < 5; ++seg) {
    const int j = seg * 256 + l * 4;
    const f32x4 a4 = *(const f32x4*)(wa + j);
    const f32x4 g4 = *(const f32x4*)(wg + j);
#pragma unroll
    for (int b = 0; b < 4; ++b) {
      const f32x4 yv = *(const f32x4*)(y63 + b * HDIM + j);
      sa[b] += a4.x * yv.x + a4.y * yv.y + a4.z * yv.z + a4.w * yv.w;
      sg[b] += g4.x * yv.x + g4.y * yv.y + g4.z * yv.z + g4.w * yv.w;
    }
  }
#pragma unroll
  for (int off = 32; off; off >>= 1)
#pragma unroll
    for (int b = 0; b < 4; ++b) {
      sa[b] += __shfl_down(sa[b], off);
      sg[b] += __shfl_down(sg[b], off);
    }
  if (l == 0) {
    const float ba = bc[r], bg = bc[HDIM + r];
#pragma unroll
    for (int b = 0; b < 4; ++b) {
      const float za = ba + sa[b], zg = bg + sg[b];
      lastv[b * HDIM + r] = za / (1.f + expf(-zg));
    }
  }
}

// ---------------------------------------------------------------------------
// K6: head  h1 = relu(last @ W1^T + b1); out = h1 @ W2^T + b2
// ---------------------------------------------------------------------------
__global__ __launch_bounds__(64) void k_head(
    const float* __restrict__ lastv, const float* __restrict__ W1,
    const float* __restrict__ b1, const float* __restrict__ W2,
    const float* __restrict__ b2, float* __restrict__ out) {
  __shared__ float ll[HDIM];
  __shared__ float h1[64];
  const int b = blockIdx.x, t = threadIdx.x;
  for (int i = t; i < HDIM; i += 64) ll[i] = lastv[b * HDIM + i];
  __syncthreads();
  {
    const float* w = W1 + t * HDIM;
    float s = b1[t];
    for (int j = 0; j < HDIM; j += 4) {
      const f32x4 wv = *(const f32x4*)(w + j);
      s += wv.x * ll[j] + wv.y * ll[j + 1] + wv.z * ll[j + 2] + wv.w * ll[j + 3];
    }
    h1[t] = fmaxf(s, 0.f);
  }
  __syncthreads();
  if (t < 60) {
    const float* w = W2 + t * 64;
    float o = b2[t];
#pragma unroll
    for (int r = 0; r < 64; ++r) o += w[r] * h1[r];
    out[b * 60 + t] = o;
  }
}

extern "C" void kernel_launch(void* const* d_in, const int* in_sizes, int n_in,
                              void* d_out, int out_size, void* d_ws, size_t ws_size,
                              hipStream_t stream) {
  const float* x   = (const float*)d_in[0];
  const float* Wb  = (const float*)d_in[1];
  const float* bb  = (const float*)d_in[2];
  const float* ldt = (const float*)d_in[3];
  const float* C   = (const float*)d_in[4];
  const float* lar = (const float*)d_in[5];
  const float* Dv  = (const float*)d_in[6];
  const float* Wc  = (const float*)d_in[7];
  const float* bc  = (const float*)d_in[8];
  const float* W1  = (const float*)d_in[9];
  const float* b1  = (const float*)d_in[10];
  const float* W2  = (const float*)d_in[11];
  const float* b2  = (const float*)d_in[12];
  float* out = (float*)d_out;

  float* P     = (float*)d_ws;                     // 24*256*1280 f32 = 31.5 MB
  float* ktab  = P + (long)KCHUNKS * PSTRIDE;      // 1280*64
  float* U     = ktab + HDIM * 64;                 // 256*1280
  float* y63   = U + PSTRIDE;                      // 4*1280
  float* lastv = y63 + 4 * HDIM;                   // 4*1280

  (void)hipFuncSetAttribute(reinterpret_cast<const void*>(k_gemm),
                            hipFuncAttributeMaxDynamicSharedMemorySize, 65536);

  k_s4d<<<320, 256, 0, stream>>>(ldt, lar, C, ktab);
  k_gemm<<<NT_TILES * MT_TILES * KCHUNKS, 512, 65536, stream>>>(x, Wb, P);
  k_red<<<PSTRIDE / 256, 256, 0, stream>>>(P, bb, U);
  k_conv<<<20, 256, 0, stream>>>(U, ktab, Dv, y63);
  k_gate<<<HDIM, 64, 0, stream>>>(y63, Wc, bc, lastv);
  k_head<<<4, 64, 0, stream>>>(lastv, W1, b1, W2, b2, out);
}